// Round 2
// baseline (55.182 us; speedup 1.0000x reference)
//
#include <hip/hip_runtime.h>
#include <hip/hip_fp16.h>

// QuantLinear: out[16][11008] = x[16][4096] . dequant(weight_q[11008][4096])^T + bias
// dequant: w = scale[o][i/128] * ((wq & 255) - zero[o][i/128]), group = 128.
// NOTE: harness promotes the reference's float16 tensors to float32 on push
// (its dtype universe is {bf16, f32, int32}) -> x/scale/zero/bias are float*.
// Memory-bound: weight_q stream = 180.4 MB int32 (~29us floor at 6.3 TB/s).
// Design: MFMA 16x16x32 f16 skinny GEMM, dequant fused in-register, no LDS,
// atomicAdd f32 K-reduction into bias-initialized out.

typedef _Float16 v8hf __attribute__((ext_vector_type(8)));
typedef float v4f __attribute__((ext_vector_type(4)));

#define O_DIM 11008
#define I_DIM 4096
#define NGROUP 32   // I_DIM / 128

// Re-initialize out = bias every call: harness poisons d_out once and replays
// the graph without re-poisoning; the GEMM kernel accumulates via atomicAdd.
__global__ __launch_bounds__(256) void init_out(const float* __restrict__ bias,
                                                float* __restrict__ out) {
    int t = blockIdx.x * 256 + threadIdx.x;       // t < 16*11008 = 176128 exactly
    int o = t % O_DIM;
    out[t] = bias[o];
}

// Block: o-tile (16 outputs) x K-chunk (1024 i's). 4 waves split the K-chunk
// into 2 scale-groups each (group = 128 i's = 4 MFMA K-steps of 32).
// Lane fields: col = l&15 (A-row = x-row, B-col = o), kb = l>>4 (k sub-block).
__global__ __launch_bounds__(256) void qgemm(const float* __restrict__ x,
                                             const int* __restrict__ wq,
                                             const float* __restrict__ scale,
                                             const float* __restrict__ zero,
                                             float* __restrict__ out) {
    const int b   = blockIdx.x;
    const int ot  = b >> 2;        // 0..687 o-tile
    const int kc  = b & 3;         // K-chunk 0..3
    const int tid = threadIdx.x;
    const int w   = tid >> 6;      // wave 0..3
    const int l   = tid & 63;
    const int col = l & 15;        // A-row / B-col / output col within tile
    const int kb  = l >> 4;        // k sub-block 0..3
    const int o   = ot * 16 + col;

    const int* __restrict__ wrow = wq + (size_t)o * I_DIM;

    v4f acc = {0.f, 0.f, 0.f, 0.f};

#pragma unroll
    for (int gi = 0; gi < 2; ++gi) {
        const int g = kc * 8 + w * 2 + gi;               // scale group 0..31
        const float s   = scale[o * NGROUP + g];
        const float z   = zero [o * NGROUP + g];
        const float nzs = -z * s;
#pragma unroll
        for (int ks = 0; ks < 4; ++ks) {
            const int i0 = g * 128 + ks * 32;            // K-step base (32 i's)
            const int* wp = wrow + i0 + kb * 8;          // 8 consecutive int32 = 32B
            const int4 q0 = *(const int4*)(wp);
            const int4 q1 = *(const int4*)(wp + 4);
            // A-frag: x[row = col][k = i0 + kb*8 + j], j=0..7 (f32 -> f16, L2-hot)
            const float* xp = x + (size_t)col * I_DIM + i0 + kb * 8;
            const float4 x0 = *(const float4*)(xp);
            const float4 x1 = *(const float4*)(xp + 4);
            v8hf a;
            a[0] = (_Float16)x0.x; a[1] = (_Float16)x0.y;
            a[2] = (_Float16)x0.z; a[3] = (_Float16)x0.w;
            a[4] = (_Float16)x1.x; a[5] = (_Float16)x1.y;
            a[6] = (_Float16)x1.z; a[7] = (_Float16)x1.w;
            // B-frag: dequantized weights, same k mapping as A (symmetric layout
            // => any internal k-permutation cancels between A and B).
            v8hf bf;
            bf[0] = (_Float16)((float)(q0.x & 255) * s + nzs);
            bf[1] = (_Float16)((float)(q0.y & 255) * s + nzs);
            bf[2] = (_Float16)((float)(q0.z & 255) * s + nzs);
            bf[3] = (_Float16)((float)(q0.w & 255) * s + nzs);
            bf[4] = (_Float16)((float)(q1.x & 255) * s + nzs);
            bf[5] = (_Float16)((float)(q1.y & 255) * s + nzs);
            bf[6] = (_Float16)((float)(q1.z & 255) * s + nzs);
            bf[7] = (_Float16)((float)(q1.w & 255) * s + nzs);
            acc = __builtin_amdgcn_mfma_f32_16x16x32_f16(a, bf, acc, 0, 0, 0);
        }
    }

    // C/D layout (verified m89): col = l&15, row = (l>>4)*4 + r
    float* op = out + (size_t)(kb * 4) * O_DIM + o;
#pragma unroll
    for (int r = 0; r < 4; ++r) {
        atomicAdd(op + (size_t)r * O_DIM, acc[r]);
    }
}

extern "C" void kernel_launch(void* const* d_in, const int* in_sizes, int n_in,
                              void* d_out, int out_size, void* d_ws, size_t ws_size,
                              hipStream_t stream) {
    const float* x   = (const float*)d_in[0];
    const int*   wqp = (const int*)  d_in[1];
    const float* sc  = (const float*)d_in[2];
    const float* zp  = (const float*)d_in[3];
    const float* bp  = (const float*)d_in[4];
    float* out = (float*)d_out;

    init_out<<<688, 256, 0, stream>>>(bp, out);            // 688*256 = 176128
    qgemm<<<2752, 256, 0, stream>>>(x, wqp, sc, zp, out);  // 688 o-tiles * 4 K-chunks
}

// Round 5
// 51.187 us; speedup vs baseline: 1.0780x; 1.0780x over previous
//
#include <hip/hip_runtime.h>
#include <hip/hip_fp16.h>

// QuantLinear: out[16][11008] = x[16][4096] . dequant(weight_q[11008][4096])^T + bias
// dequant: w = scale[o][i/128] * ((wq & 255) - zero[o][i/128]), group = 128.
// Harness promotes fp16 tensors to fp32 -> x/scale/zero/bias are float*.
// Memory-bound: weight_q stream = 180.4 MB (~26-29us floor at measured ~7 TB/s).
// Round-2 lesson: split-K + atomics + separate init kernel cost ~20us of overhead.
// Design: ONE kernel, one block per 16-output o-tile, full K per block.
// 4 waves split K (1024 each = 8 scale-groups); LDS cross-wave reduce; single
// coalesced store with fused bias. Zero atomics, zero extra launches.
// (Rounds 3-4: container unresponsive, no measurement; resubmitting unchanged.)

typedef _Float16 v8hf __attribute__((ext_vector_type(8)));
typedef float v4f __attribute__((ext_vector_type(4)));

#define O_DIM 11008
#define I_DIM 4096
#define NGROUP 32   // I_DIM / 128

__global__ __launch_bounds__(256) void qgemm(const float* __restrict__ x,
                                             const int* __restrict__ wq,
                                             const float* __restrict__ scale,
                                             const float* __restrict__ zero,
                                             const float* __restrict__ bias,
                                             float* __restrict__ out) {
    __shared__ float red[4][256];

    const int ot  = blockIdx.x;    // o-tile 0..687
    const int tid = threadIdx.x;
    const int w   = tid >> 6;      // wave 0..3 -> K-quarter
    const int l   = tid & 63;
    const int col = l & 15;        // A-row = x-row / B-col = o (within tile)
    const int kb  = l >> 4;        // k sub-block 0..3
    const int o   = ot * 16 + col;

    const int*   __restrict__ wrow = wq + (size_t)o * I_DIM;
    const float* __restrict__ xrow = x  + (size_t)col * I_DIM;

    v4f acc = {0.f, 0.f, 0.f, 0.f};

    // Wave w handles scale-groups [w*8, w*8+8) = K range [w*1024, (w+1)*1024).
#pragma unroll 2
    for (int gi = 0; gi < 8; ++gi) {
        const int g = w * 8 + gi;
        const float s   = scale[o * NGROUP + g];
        const float z   = zero [o * NGROUP + g];
        const float nzs = -z * s;
#pragma unroll
        for (int ks = 0; ks < 4; ++ks) {
            const int i0 = g * 128 + ks * 32 + kb * 8;   // this lane's 8 k's
            const int4   q0 = *(const int4*)  (wrow + i0);
            const int4   q1 = *(const int4*)  (wrow + i0 + 4);
            const float4 x0 = *(const float4*)(xrow + i0);
            const float4 x1 = *(const float4*)(xrow + i0 + 4);
            v8hf a;
            a[0] = (_Float16)x0.x; a[1] = (_Float16)x0.y;
            a[2] = (_Float16)x0.z; a[3] = (_Float16)x0.w;
            a[4] = (_Float16)x1.x; a[5] = (_Float16)x1.y;
            a[6] = (_Float16)x1.z; a[7] = (_Float16)x1.w;
            // B-frag: same (lane,j)->k mapping as A => internal k-permutation cancels.
            v8hf bf;
            bf[0] = (_Float16)((float)(q0.x & 255) * s + nzs);
            bf[1] = (_Float16)((float)(q0.y & 255) * s + nzs);
            bf[2] = (_Float16)((float)(q0.z & 255) * s + nzs);
            bf[3] = (_Float16)((float)(q0.w & 255) * s + nzs);
            bf[4] = (_Float16)((float)(q1.x & 255) * s + nzs);
            bf[5] = (_Float16)((float)(q1.y & 255) * s + nzs);
            bf[6] = (_Float16)((float)(q1.z & 255) * s + nzs);
            bf[7] = (_Float16)((float)(q1.w & 255) * s + nzs);
            acc = __builtin_amdgcn_mfma_f32_16x16x32_f16(a, bf, acc, 0, 0, 0);
        }
    }

    // Cross-wave K-reduction. acc[r] = tile element (row=(l>>4)*4+r, col=l&15).
    *(v4f*)&red[w][l * 4] = acc;   // lane-contiguous 16B stores, conflict-free
    __syncthreads();

    // 256 threads: sum 4 waves' partials, add bias, store (each element once).
    const int t   = tid;
    const float sum = red[0][t] + red[1][t] + red[2][t] + red[3][t];
    const int l2  = t >> 2;                 // original lane
    const int r   = t & 3;                  // acc register index
    const int row = (l2 >> 4) * 4 + r;      // x-row 0..15
    const int oc  = ot * 16 + (l2 & 15);    // output column
    out[(size_t)row * O_DIM + oc] = sum + bias[oc];
}

extern "C" void kernel_launch(void* const* d_in, const int* in_sizes, int n_in,
                              void* d_out, int out_size, void* d_ws, size_t ws_size,
                              hipStream_t stream) {
    const float* x   = (const float*)d_in[0];
    const int*   wqp = (const int*)  d_in[1];
    const float* sc  = (const float*)d_in[2];
    const float* zp  = (const float*)d_in[3];
    const float* bp  = (const float*)d_in[4];
    float* out = (float*)d_out;

    qgemm<<<688, 256, 0, stream>>>(x, wqp, sc, zp, bp, out);  // one block per o-tile
}